// Round 8
// baseline (134.973 us; speedup 1.0000x reference)
//
#include <hip/hip_runtime.h>
#include <hip/hip_cooperative_groups.h>

namespace cg = cooperative_groups;

#define NN 20000
#define VV 100000
#define CC 5000
#define MM 32
#define KK 2048
#define DD 128

#define NBLK 250
#define NTHR 512
#define NTILE 625  // NN/32

// ws: active[CC] @0 ; memb @32768 (2.56MB) ; w1t bf16 @2592768 (96KB) ; w3t bf16 @2691072 (16KB)
#define WS_MEMB 32768
#define WS_W1T  2592768
#define WS_W3T  2691072

typedef __attribute__((ext_vector_type(8))) short bf16x8;
typedef __attribute__((ext_vector_type(4))) float f32x4;

__device__ __forceinline__ unsigned f2bf_rne(float f) {  // bf16 in low 16 bits
  unsigned u = __builtin_bit_cast(unsigned, f);
  u += 0x7fffu + ((u >> 16) & 1u);
  return u >> 16;
}
__device__ __forceinline__ float bf2f(unsigned h) {
  unsigned u = h << 16;
  return __builtin_bit_cast(float, u);
}

struct Params {
  const float* node_emb; const float* mscore; const float* cemb;
  const float* W1; const float* b1; const float* W2; const float* b2;
  const float* W3; const float* b3; const float* W4; const float* b4;
  const int* n2c; const int* c2n; const int* mnum; const int* cidx; const int* nodes;
  float* out; int* active; float* memb;
  unsigned short* w1t; unsigned short* w3t;
};

// One cooperative dispatch; 4 phases separated by grid.sync().
__global__ __launch_bounds__(NTHR) void fused_coop_k(Params p) {
  __shared__ __align__(16) unsigned short s_b[128][392];   // 98 KB, W1^T resident all phases
  __shared__ __align__(16) unsigned short s_hi[32][392];   // 24.5 KB
  __shared__ __align__(16) unsigned short s_lo[32][392];   // 24.5 KB
  __shared__ int s_v[32], s_cm[32], s_use[32];
  __shared__ float s_r1[32][4], s_r2[32][4];
  cg::grid_group grid = cg::this_grid();
  int tid = threadIdx.x;
  int b = blockIdx.x;
  int gtid = b * NTHR + tid;  // < 128000

  // ---- A1: convert W1->bf16^T, W3->bf16^T; zero active ----
  if (gtid < 3 * DD * DD) {                 // w1t[c][k]: 49152
    int c = gtid / 384, k = gtid % 384;
    p.w1t[gtid] = (unsigned short)f2bf_rne(p.W1[(size_t)k * DD + c]);
  } else if (gtid - 49152 < 64 * DD) {      // w3t[h][k]: 8192
    int e = gtid - 49152;
    int h = e >> 7, k = e & 127;
    p.w3t[e] = (unsigned short)f2bf_rne(p.W3[(size_t)k * 64 + h]);
  } else if (gtid - 57344 < CC) {
    p.active[gtid - 57344] = 0;
  }
  grid.sync();

  // ---- A2: scatter active; stage W1^T into LDS (once per block) ----
  if (gtid < KK) p.active[p.cidx[gtid]] = 1;
  {
    const uint4* src = (const uint4*)p.w1t;  // 6144 uint4
    #pragma unroll
    for (int it = 0; it < 12; ++it) {
      int i = it * NTHR + tid;
      int row = i / 48, c16 = i % 48;
      *(uint4*)((char*)&s_b[0][0] + row * 784 + c16 * 16) = src[i];
    }
  }
  grid.sync();

  // ---- B: member embedding for active communities (shfl-broadcast, no LDS) ----
  {
    int lane = tid & 63;
    int half = (tid >> 6) & 1;
    int sub = tid >> 7;  // 0..3 communities per iteration
    int d = half * 64 + lane;  // covers 0..127 across the wave pair
    for (int it = 0; it < 5; ++it) {
      int c = it * 1000 + b * 4 + sub;  // < 5000
      if (p.active[c]) {
        float sc = 0.f; int nc = 0;
        if (lane < 32) {
          int mem = p.c2n[c * MM + lane];
          nc = p.n2c[mem];
          bool valid = (lane < p.mnum[c]) && (p.active[nc] != 0);
          sc = valid ? p.mscore[c * MM + lane] : 0.f;
        }
        float acc = 0.f;
        #pragma unroll
        for (int m = 0; m < MM; ++m) {
          float s = __shfl(sc, m, 64);
          int ncm = __shfl(nc, m, 64);
          acc = fmaf(s, p.cemb[(size_t)ncm * DD + d], acc);
        }
        p.memb[(size_t)c * DD + d] = acc;
      }
    }
  }
  grid.sync();

  // ---- C: per-tile feat stage + pred1 MFMA + pred2 MFMA + select ----
  int lane = tid & 63, w = tid >> 6;
  int rt = w & 1;
  int lrow = lane & 15, lkq = lane >> 4, lkb = lkq * 8;
  int ch = w >> 1;  // col-tile for pred1 / hidden-tile for pred2
  for (int t = b; t < NTILE; t += NBLK) {
    int n0 = t * 32;
    if (tid < 32) {
      int v = p.nodes[n0 + tid], cm = p.n2c[v];
      s_v[tid] = v; s_cm[tid] = cm; s_use[tid] = p.active[cm];
    }
    __syncthreads();
    {  // stage feat hi/lo: 32 rows x 96 float4
      #pragma unroll
      for (int it = 0; it < 6; ++it) {
        int i4 = it * NTHR + tid;
        int row = i4 / 96, pos = i4 % 96;
        int off = pos * 4;
        int use = s_use[row];
        float4 f;
        if (off < DD) {
          f = *(const float4*)(p.node_emb + (size_t)(n0 + row) * DD + off);
        } else if (off < 2 * DD) {
          f = use ? *(const float4*)(p.cemb + (size_t)s_v[row] * DD + (off - DD))
                  : make_float4(0.f, 0.f, 0.f, 0.f);
        } else {
          f = use ? *(const float4*)(p.memb + (size_t)s_cm[row] * DD + (off - 2 * DD))
                  : make_float4(0.f, 0.f, 0.f, 0.f);
        }
        unsigned h0 = f2bf_rne(f.x), h1 = f2bf_rne(f.y),
                 h2 = f2bf_rne(f.z), h3 = f2bf_rne(f.w);
        unsigned l0 = f2bf_rne(f.x - bf2f(h0)), l1 = f2bf_rne(f.y - bf2f(h1)),
                 l2 = f2bf_rne(f.z - bf2f(h2)), l3 = f2bf_rne(f.w - bf2f(h3));
        *(uint2*)&s_hi[row][off] = make_uint2(h0 | (h1 << 16), h2 | (h3 << 16));
        *(uint2*)&s_lo[row][off] = make_uint2(l0 | (l1 << 16), l2 | (l3 << 16));
      }
    }
    __syncthreads();
    const char* ah = (const char*)&s_hi[rt * 16 + lrow][0] + lkb * 2;
    const char* al = (const char*)&s_lo[rt * 16 + lrow][0] + lkb * 2;
    // pred1: cols ch*32 .. +31
    {
      const char* bp0 = (const char*)&s_b[ch * 32 + lrow][0] + lkb * 2;
      const char* bp1 = bp0 + 16 * 784;
      f32x4 acc0 = {0.f, 0.f, 0.f, 0.f}, acc1 = {0.f, 0.f, 0.f, 0.f};
      #pragma unroll
      for (int k0 = 0; k0 < 3 * DD; k0 += 32) {
        bf16x8 vah = *(const bf16x8*)(ah + k0 * 2);
        bf16x8 val = *(const bf16x8*)(al + k0 * 2);
        bf16x8 vb0 = *(const bf16x8*)(bp0 + k0 * 2);
        bf16x8 vb1 = *(const bf16x8*)(bp1 + k0 * 2);
        acc0 = __builtin_amdgcn_mfma_f32_16x16x32_bf16(vah, vb0, acc0, 0, 0, 0);
        acc0 = __builtin_amdgcn_mfma_f32_16x16x32_bf16(val, vb0, acc0, 0, 0, 0);
        acc1 = __builtin_amdgcn_mfma_f32_16x16x32_bf16(vah, vb1, acc1, 0, 0, 0);
        acc1 = __builtin_amdgcn_mfma_f32_16x16x32_bf16(val, vb1, acc1, 0, 0, 0);
      }
      int c0 = ch * 32 + lrow, c1 = c0 + 16;
      float b1a = p.b1[c0], b1b = p.b1[c1];
      float w2a = p.W2[c0], w2b = p.W2[c1];
      float vsum[4];
      #pragma unroll
      for (int j = 0; j < 4; ++j)
        vsum[j] = fmaxf(acc0[j] + b1a, 0.f) * w2a + fmaxf(acc1[j] + b1b, 0.f) * w2b;
      #pragma unroll
      for (int m = 1; m <= 8; m <<= 1)
        #pragma unroll
        for (int j = 0; j < 4; ++j) vsum[j] += __shfl_xor(vsum[j], m, 64);
      if (lrow == 0) {
        #pragma unroll
        for (int j = 0; j < 4; ++j) s_r1[rt * 16 + lkq * 4 + j][ch] = vsum[j];
      }
    }
    // pred2: hidden cols ch*16 .. +15, K=128 over node_emb part
    {
      const unsigned short* w3p = p.w3t + (size_t)(ch * 16 + lrow) * DD + lkb;
      f32x4 p2 = {0.f, 0.f, 0.f, 0.f};
      #pragma unroll
      for (int k0 = 0; k0 < DD; k0 += 32) {
        bf16x8 vb = *(const bf16x8*)(w3p + k0);
        bf16x8 vah = *(const bf16x8*)(ah + k0 * 2);
        bf16x8 val = *(const bf16x8*)(al + k0 * 2);
        p2 = __builtin_amdgcn_mfma_f32_16x16x32_bf16(vah, vb, p2, 0, 0, 0);
        p2 = __builtin_amdgcn_mfma_f32_16x16x32_bf16(val, vb, p2, 0, 0, 0);
      }
      int h = ch * 16 + lrow;
      float b3v = p.b3[h], w4v = p.W4[h];
      float q[4];
      #pragma unroll
      for (int j = 0; j < 4; ++j) q[j] = fmaxf(p2[j] + b3v, 0.f) * w4v;
      #pragma unroll
      for (int m = 1; m <= 8; m <<= 1)
        #pragma unroll
        for (int j = 0; j < 4; ++j) q[j] += __shfl_xor(q[j], m, 64);
      if (lrow == 0) {
        #pragma unroll
        for (int j = 0; j < 4; ++j) s_r2[rt * 16 + lkq * 4 + j][ch] = q[j];
      }
    }
    __syncthreads();
    if (tid < 32) {
      float r;
      if (s_use[tid])
        r = s_r1[tid][0] + s_r1[tid][1] + s_r1[tid][2] + s_r1[tid][3] + p.b2[0];
      else
        r = s_r2[tid][0] + s_r2[tid][1] + s_r2[tid][2] + s_r2[tid][3] + p.b4[0];
      p.out[n0 + tid] = r;
    }
    __syncthreads();
  }
}

extern "C" void kernel_launch(void* const* d_in, const int* in_sizes, int n_in,
                              void* d_out, int out_size, void* d_ws, size_t ws_size,
                              hipStream_t stream) {
  Params p;
  p.node_emb = (const float*)d_in[0];
  p.mscore   = (const float*)d_in[1];
  p.cemb     = (const float*)d_in[2];
  p.W1 = (const float*)d_in[3];
  p.b1 = (const float*)d_in[4];
  p.W2 = (const float*)d_in[5];
  p.b2 = (const float*)d_in[6];
  p.W3 = (const float*)d_in[7];
  p.b3 = (const float*)d_in[8];
  p.W4 = (const float*)d_in[9];
  p.b4 = (const float*)d_in[10];
  p.n2c   = (const int*)d_in[11];
  p.c2n   = (const int*)d_in[12];
  p.mnum  = (const int*)d_in[13];
  p.cidx  = (const int*)d_in[14];
  p.nodes = (const int*)d_in[15];
  p.out = (float*)d_out;
  p.active = (int*)d_ws;
  p.memb = (float*)((char*)d_ws + WS_MEMB);
  p.w1t = (unsigned short*)((char*)d_ws + WS_W1T);
  p.w3t = (unsigned short*)((char*)d_ws + WS_W3T);

  void* kargs[] = {&p};
  hipLaunchCooperativeKernel((const void*)fused_coop_k, dim3(NBLK), dim3(NTHR),
                             kargs, 0, stream);
}

// Round 9
// 40.965 us; speedup vs baseline: 3.2948x; 3.2948x over previous
//
#include <hip/hip_runtime.h>

#define NN 20000
#define VV 100000
#define CC 5000
#define MM 32
#define KK 2048
#define DD 128

// ws: active[CC] @0 ; memb @32768 (2.56MB) ; w1t bf16 @2592768 (96KB) ; w3t bf16 @2691072 (16KB)
#define WS_MEMB 32768
#define WS_W1T  2592768
#define WS_W3T  2691072

typedef __attribute__((ext_vector_type(8))) short bf16x8;
typedef __attribute__((ext_vector_type(4))) float f32x4;

__device__ __forceinline__ unsigned f2bf_rne(float f) {  // bf16 in low 16 bits
  unsigned u = __builtin_bit_cast(unsigned, f);
  u += 0x7fffu + ((u >> 16) & 1u);
  return u >> 16;
}
__device__ __forceinline__ float bf2f(unsigned h) {
  unsigned u = h << 16;
  return __builtin_bit_cast(float, u);
}

// ---------------- K0: init = zero+scatter (block 0) | W1->bf16^T | W3->bf16^T ----------------
__global__ __launch_bounds__(256) void init_k(const int* __restrict__ cidx,
    int* __restrict__ active, const float* __restrict__ W1,
    unsigned short* __restrict__ w1t, const float* __restrict__ W3,
    unsigned short* __restrict__ w3t) {
  int b = blockIdx.x, tid = threadIdx.x;
  if (b == 0) {
    for (int i = tid; i < CC; i += 256) active[i] = 0;
    __syncthreads();
    for (int k = tid; k < KK; k += 256) active[cidx[k]] = 1;
  } else if (b <= 192) {
    int i = (b - 1) * 256 + tid;        // 0..49151 ; w1t[c][k], c<128, k<384
    int c = i / 384, k = i % 384;
    w1t[i] = (unsigned short)f2bf_rne(W1[(size_t)k * DD + c]);
  } else {                               // b == 193 ; w3t[h][k], h<64, k<128
    for (int i = tid; i < 64 * DD; i += 256) {
      int h = i >> 7, k = i & 127;
      w3t[i] = (unsigned short)f2bf_rne(W3[(size_t)k * 64 + h]);
    }
  }
}

// ---------------- K1: member embedding, driven by cidx (2048 blocks) ----------------
// Duplicate cidx entries recompute identical values - deterministic.
__global__ __launch_bounds__(128) void member_emb_k(const int* __restrict__ c2n,
    const int* __restrict__ n2c, const float* __restrict__ mscore,
    const int* __restrict__ mnum, const int* __restrict__ active,
    const int* __restrict__ cidx, const float* __restrict__ cemb,
    float* __restrict__ memb) {
  int c = cidx[blockIdx.x];  // active by construction
  __shared__ float s_sc[MM];
  __shared__ int s_nc[MM];
  int t = threadIdx.x;  // 0..127 = d
  if (t < MM) {
    int mem = c2n[c * MM + t];
    int nc = n2c[mem];
    bool valid = (t < mnum[c]) && (active[nc] != 0);
    s_nc[t] = nc;
    s_sc[t] = valid ? mscore[c * MM + t] : 0.f;
  }
  __syncthreads();
  float acc = 0.f;
  #pragma unroll
  for (int m = 0; m < MM; ++m)  // 32 independent loads in flight
    acc = fmaf(s_sc[m], cemb[(size_t)s_nc[m] * DD + t], acc);
  memb[(size_t)c * DD + t] = acc;
}

// ---------------- K2: main = feat stage + pred1/pred2 MFMA + select ----------------
// 512 thr, 32 nodes/block, 625 blocks. LDS = feat hi/lo only (~51 KB -> 2 blocks/CU).
// B-fragments (W1t, W3t bf16) read directly from global (L2-resident, 60 MB total).
// Wave w: rt=w&1 -> rows rt*16..+15; ch=w>>1 -> pred1 cols ch*32..+31 / pred2 hidden ch*16..+15.
// C/D mapping (verified R6): out_row = rt*16 + (lane>>4)*4 + j, col = tile_base + (lane&15).
__global__ __launch_bounds__(512) void main_k(const float* __restrict__ node_emb,
    const float* __restrict__ cemb, const float* __restrict__ memb,
    const unsigned short* __restrict__ w1t, const float* __restrict__ b1,
    const float* __restrict__ W2, const float* __restrict__ b2v,
    const unsigned short* __restrict__ w3t, const float* __restrict__ b3,
    const float* __restrict__ W4, const float* __restrict__ b4v,
    const int* __restrict__ n2c, const int* __restrict__ active,
    const int* __restrict__ nodes, float* __restrict__ out) {
  __shared__ __align__(16) unsigned short s_hi[32][392];   // 24.5 KB
  __shared__ __align__(16) unsigned short s_lo[32][392];   // 24.5 KB
  __shared__ int s_v[32], s_cm[32], s_use[32];
  __shared__ float s_r1[32][4], s_r2[32][4];
  int tid = threadIdx.x;
  int n0 = blockIdx.x * 32;
  if (tid < 32) {
    int v = nodes[n0 + tid], cm = n2c[v];
    s_v[tid] = v; s_cm[tid] = cm; s_use[tid] = active[cm];
  }
  __syncthreads();
  {  // stage feat hi/lo: 32 rows x 96 float4
    #pragma unroll
    for (int it = 0; it < 6; ++it) {
      int i4 = it * 512 + tid;
      int row = i4 / 96, pos = i4 % 96;
      int off = pos * 4;
      int use = s_use[row];
      float4 f;
      if (off < DD) {
        f = *(const float4*)(node_emb + (size_t)(n0 + row) * DD + off);
      } else if (off < 2 * DD) {
        f = use ? *(const float4*)(cemb + (size_t)s_v[row] * DD + (off - DD))
                : make_float4(0.f, 0.f, 0.f, 0.f);
      } else {
        f = use ? *(const float4*)(memb + (size_t)s_cm[row] * DD + (off - 2 * DD))
                : make_float4(0.f, 0.f, 0.f, 0.f);
      }
      unsigned h0 = f2bf_rne(f.x), h1 = f2bf_rne(f.y),
               h2 = f2bf_rne(f.z), h3 = f2bf_rne(f.w);
      unsigned l0 = f2bf_rne(f.x - bf2f(h0)), l1 = f2bf_rne(f.y - bf2f(h1)),
               l2 = f2bf_rne(f.z - bf2f(h2)), l3 = f2bf_rne(f.w - bf2f(h3));
      *(uint2*)&s_hi[row][off] = make_uint2(h0 | (h1 << 16), h2 | (h3 << 16));
      *(uint2*)&s_lo[row][off] = make_uint2(l0 | (l1 << 16), l2 | (l3 << 16));
    }
  }
  __syncthreads();
  int lane = tid & 63, w = tid >> 6;
  int rt = w & 1, ch = w >> 1;
  int lrow = lane & 15, lkq = lane >> 4, lkb = lkq * 8;
  const char* ah = (const char*)&s_hi[rt * 16 + lrow][0] + lkb * 2;
  const char* al = (const char*)&s_lo[rt * 16 + lrow][0] + lkb * 2;
  // B pointers: w1t row = output col (384 bf16/row); w3t row = hidden col (128 bf16/row)
  const unsigned short* bp0 = w1t + (size_t)(ch * 32 + lrow) * 384 + lkb;
  const unsigned short* bp1 = bp0 + 16 * 384;
  const unsigned short* w3p = w3t + (size_t)(ch * 16 + lrow) * DD + lkb;
  f32x4 acc0 = {0.f, 0.f, 0.f, 0.f}, acc1 = {0.f, 0.f, 0.f, 0.f};
  f32x4 p2   = {0.f, 0.f, 0.f, 0.f};
  #pragma unroll
  for (int k0 = 0; k0 < DD; k0 += 32) {  // pred1 + pred2 share A-frags
    bf16x8 vah = *(const bf16x8*)(ah + k0 * 2);
    bf16x8 val = *(const bf16x8*)(al + k0 * 2);
    bf16x8 vb0 = *(const bf16x8*)(bp0 + k0);
    bf16x8 vb1 = *(const bf16x8*)(bp1 + k0);
    bf16x8 vb2 = *(const bf16x8*)(w3p + k0);
    acc0 = __builtin_amdgcn_mfma_f32_16x16x32_bf16(vah, vb0, acc0, 0, 0, 0);
    acc0 = __builtin_amdgcn_mfma_f32_16x16x32_bf16(val, vb0, acc0, 0, 0, 0);
    acc1 = __builtin_amdgcn_mfma_f32_16x16x32_bf16(vah, vb1, acc1, 0, 0, 0);
    acc1 = __builtin_amdgcn_mfma_f32_16x16x32_bf16(val, vb1, acc1, 0, 0, 0);
    p2   = __builtin_amdgcn_mfma_f32_16x16x32_bf16(vah, vb2, p2, 0, 0, 0);
    p2   = __builtin_amdgcn_mfma_f32_16x16x32_bf16(val, vb2, p2, 0, 0, 0);
  }
  #pragma unroll
  for (int k0 = DD; k0 < 3 * DD; k0 += 32) {  // pred1 only
    bf16x8 vah = *(const bf16x8*)(ah + k0 * 2);
    bf16x8 val = *(const bf16x8*)(al + k0 * 2);
    bf16x8 vb0 = *(const bf16x8*)(bp0 + k0);
    bf16x8 vb1 = *(const bf16x8*)(bp1 + k0);
    acc0 = __builtin_amdgcn_mfma_f32_16x16x32_bf16(vah, vb0, acc0, 0, 0, 0);
    acc0 = __builtin_amdgcn_mfma_f32_16x16x32_bf16(val, vb0, acc0, 0, 0, 0);
    acc1 = __builtin_amdgcn_mfma_f32_16x16x32_bf16(vah, vb1, acc1, 0, 0, 0);
    acc1 = __builtin_amdgcn_mfma_f32_16x16x32_bf16(val, vb1, acc1, 0, 0, 0);
  }
  {  // pred1 epilogue
    int c0 = ch * 32 + lrow, c1 = c0 + 16;
    float b1a = b1[c0], b1b = b1[c1];
    float w2a = W2[c0], w2b = W2[c1];
    float vsum[4];
    #pragma unroll
    for (int j = 0; j < 4; ++j)
      vsum[j] = fmaxf(acc0[j] + b1a, 0.f) * w2a + fmaxf(acc1[j] + b1b, 0.f) * w2b;
    #pragma unroll
    for (int m = 1; m <= 8; m <<= 1)
      #pragma unroll
      for (int j = 0; j < 4; ++j) vsum[j] += __shfl_xor(vsum[j], m, 64);
    if (lrow == 0) {
      #pragma unroll
      for (int j = 0; j < 4; ++j) s_r1[rt * 16 + lkq * 4 + j][ch] = vsum[j];
    }
  }
  {  // pred2 epilogue
    int h = ch * 16 + lrow;
    float b3v = b3[h], w4v = W4[h];
    float q[4];
    #pragma unroll
    for (int j = 0; j < 4; ++j) q[j] = fmaxf(p2[j] + b3v, 0.f) * w4v;
    #pragma unroll
    for (int m = 1; m <= 8; m <<= 1)
      #pragma unroll
      for (int j = 0; j < 4; ++j) q[j] += __shfl_xor(q[j], m, 64);
    if (lrow == 0) {
      #pragma unroll
      for (int j = 0; j < 4; ++j) s_r2[rt * 16 + lkq * 4 + j][ch] = q[j];
    }
  }
  __syncthreads();
  if (tid < 32) {
    float r;
    if (s_use[tid])
      r = s_r1[tid][0] + s_r1[tid][1] + s_r1[tid][2] + s_r1[tid][3] + b2v[0];
    else
      r = s_r2[tid][0] + s_r2[tid][1] + s_r2[tid][2] + s_r2[tid][3] + b4v[0];
    out[n0 + tid] = r;
  }
}

extern "C" void kernel_launch(void* const* d_in, const int* in_sizes, int n_in,
                              void* d_out, int out_size, void* d_ws, size_t ws_size,
                              hipStream_t stream) {
  const float* node_emb = (const float*)d_in[0];
  const float* mscore   = (const float*)d_in[1];
  const float* cemb     = (const float*)d_in[2];
  const float* W1 = (const float*)d_in[3];
  const float* b1 = (const float*)d_in[4];
  const float* W2 = (const float*)d_in[5];
  const float* b2 = (const float*)d_in[6];
  const float* W3 = (const float*)d_in[7];
  const float* b3 = (const float*)d_in[8];
  const float* W4 = (const float*)d_in[9];
  const float* b4 = (const float*)d_in[10];
  const int* n2c   = (const int*)d_in[11];
  const int* c2n   = (const int*)d_in[12];
  const int* mnum  = (const int*)d_in[13];
  const int* cidx  = (const int*)d_in[14];
  const int* nodes = (const int*)d_in[15];
  float* out = (float*)d_out;

  int* active = (int*)d_ws;
  float* memb = (float*)((char*)d_ws + WS_MEMB);
  unsigned short* w1t = (unsigned short*)((char*)d_ws + WS_W1T);
  unsigned short* w3t = (unsigned short*)((char*)d_ws + WS_W3T);

  init_k<<<194, 256, 0, stream>>>(cidx, active, W1, w1t, W3, w3t);
  member_emb_k<<<KK, 128, 0, stream>>>(c2n, n2c, mscore, mnum, active, cidx,
                                       cemb, memb);
  main_k<<<NN / 32, 512, 0, stream>>>(node_emb, cemb, memb, w1t, b1, W2, b2,
                                      w3t, b3, W4, b4, n2c, active, nodes, out);
}